// Round 8
// baseline (143.218 us; speedup 1.0000x reference)
//
#include <hip/hip_runtime.h>
#include <hip/hip_bf16.h>

// Problem constants
#define NB 32     // batch
#define NL 2048   // seq len
#define ND 1024   // DQ = DK = NH*DH
#define NHH 16    // heads
#define NDH 64    // head dim

typedef __bf16 bf16;
typedef __attribute__((ext_vector_type(8))) __bf16 bf16x8;
typedef __attribute__((ext_vector_type(4))) float f32x4;

__device__ __forceinline__ float dot4(float4 a, float4 b) {
  return a.x * b.x + a.y * b.y + a.z * b.z + a.w * b.w;
}

// ---------------------------------------------------------------------------
// K1: qs[b][o] = q[b] . Wq[o] + bq[o]      grid=1024, block=256
// ---------------------------------------------------------------------------
__global__ __launch_bounds__(256) void qs_kernel(
    const float* __restrict__ q, const float* __restrict__ Wq,
    const float* __restrict__ bq, float* __restrict__ qs) {
  int o = blockIdx.x;
  int lane = threadIdx.x & 63;
  int wv = threadIdx.x >> 6;
  const float4* wrow = reinterpret_cast<const float4*>(Wq + (size_t)o * ND) + lane * 4;
  float4 w0 = wrow[0], w1 = wrow[1], w2 = wrow[2], w3 = wrow[3];
#pragma unroll
  for (int bb = 0; bb < 8; ++bb) {
    int b = wv * 8 + bb;
    const float4* qr = reinterpret_cast<const float4*>(q + (size_t)b * ND) + lane * 4;
    float s = dot4(qr[0], w0) + dot4(qr[1], w1) + dot4(qr[2], w2) + dot4(qr[3], w3);
#pragma unroll
    for (int off = 32; off > 0; off >>= 1) s += __shfl_down(s, off, 64);
    if (lane == 0) qs[(size_t)b * ND + o] = s + bq[o];
  }
}

// ---------------------------------------------------------------------------
// K2: qt[b][n][i] = sum_d Wk[n*64+d][i] * qs[b][n*64+d]   grid=64
// ---------------------------------------------------------------------------
__global__ __launch_bounds__(256) void qt_kernel(
    const float* __restrict__ Wk, const float* __restrict__ qs,
    float* __restrict__ qt) {
  int n = blockIdx.x >> 2;
  int ic = blockIdx.x & 3;
  int i = ic * 256 + threadIdx.x;
  __shared__ float s_qs[32][64];
  for (int t = threadIdx.x; t < 2048; t += 256) {
    int b = t >> 6, d = t & 63;
    s_qs[b][d] = qs[(size_t)b * ND + n * NDH + d];
  }
  __syncthreads();
  float acc[32];
#pragma unroll
  for (int b = 0; b < 32; ++b) acc[b] = 0.f;
  for (int d = 0; d < 64; ++d) {
    float w = Wk[((size_t)(n * NDH + d)) * ND + i];
#pragma unroll
    for (int b = 0; b < 32; ++b) acc[b] += w * s_qs[b][d];
  }
#pragma unroll
  for (int b = 0; b < 32; ++b)
    qt[((size_t)(b * NHH + n)) * ND + i] = acc[b];
}

// ---------------------------------------------------------------------------
// K2b: qb[b*16+n] = qs[b][n*64+:] . bk[n*64+:]    grid=2, block=256
// ---------------------------------------------------------------------------
__global__ __launch_bounds__(256) void qb_kernel(
    const float* __restrict__ qs, const float* __restrict__ bk,
    float* __restrict__ qb) {
  int t = blockIdx.x * 256 + threadIdx.x;
  if (t >= 512) return;
  int b = t >> 4, n = t & 15;
  float s = 0.f;
  for (int d = 0; d < 64; ++d)
    s += qs[(size_t)b * ND + n * NDH + d] * bk[n * NDH + d];
  qb[t] = s;
}

// ---------------------------------------------------------------------------
// K3 (FUSED v5): NO k staging in LDS. grid = 32b x 16sl = 512 blocks,
// 512 threads (8 waves). Per 16-l tile:
//   phase A: logits MFMA, B-fragments read DIRECTLY from global (L2-hot);
//            8 waves split kc (128 each); partials -> pbuf.
//   reduce:  tid<256 sums partials, exp -> sP + attn (unnormalized).
//   phase B: ctx += p * k, k re-read from global fully coalesced (L2 hit);
//            thread owns (nh: 8 heads) x (ic: 4 cols), all 16 l.
// LDS = pbuf+sP only (~12 KB) -> occupancy-driven overlap, 2 barriers/tile.
// HBM sees k exactly once (L2 absorbs the intra-tile re-read).
// ---------------------------------------------------------------------------
__global__ __launch_bounds__(512, 4) void fused_kernel(
    const float* __restrict__ kin, const float* __restrict__ qt,
    const float* __restrict__ qb, float* __restrict__ attn,
    float* __restrict__ ctxp) {
  int bx = blockIdx.x;
  int b  = bx >> 4;
  int sl = bx & 15;
  int tid = threadIdx.x, lane = tid & 63, wv = tid >> 6;
  int kg = lane >> 4;       // 0..3
  int ln16 = lane & 15;

  __shared__ __align__(16) float pbuf[8][16][20];  // [wave][l][n] (80B rows)
  __shared__ __align__(16) float sP[16][20];       // [l][n]

  // afrag: qt[b][n=ln16][wv*128 + mm*32 + kg*8 + 0..7]  (bf16)
  bf16x8 afrag[4];
  {
    const float* qrow = qt + ((size_t)(b * NHH + ln16)) * ND + wv * 128 + kg * 8;
#pragma unroll
    for (int mm = 0; mm < 4; ++mm) {
      f32x4 f0 = *reinterpret_cast<const f32x4*>(qrow + mm * 32);
      f32x4 f1 = *reinterpret_cast<const f32x4*>(qrow + mm * 32 + 4);
      bf16x8 v;
      v[0] = (bf16)f0[0]; v[1] = (bf16)f0[1]; v[2] = (bf16)f0[2]; v[3] = (bf16)f0[3];
      v[4] = (bf16)f1[0]; v[5] = (bf16)f1[1]; v[6] = (bf16)f1[2]; v[7] = (bf16)f1[3];
      afrag[mm] = v;
    }
  }

  // reduce-phase personals (tid<256): (l = tid&15, n = tid>>4)
  int rn = tid >> 4, rl = tid & 15;
  float qbv = (tid < 256) ? qb[b * NHH + rn] : 0.f;

  // phase-B personals: thread covers n = nh*8..+7, i = ic*4..+3, all 16 l
  int ic = tid & 255, nh = tid >> 8;
  f32x4 ctxa[8];
#pragma unroll
  for (int n = 0; n < 8; ++n) ctxa[n] = (f32x4){0.f, 0.f, 0.f, 0.f};

  const char* kbase = (const char*)(kin + ((size_t)(b * NL + sl * 128)) * ND);

  for (int t = 0; t < 8; ++t) {
    const char* ktile = kbase + (size_t)t * 16 * 4096;

    // phase A: partial logits; wave covers kc = wv*128 .. +127.
    // B-fragments straight from global (row ln16, 8 consecutive f32).
    f32x4 acc = {0.f, 0.f, 0.f, 0.f};
#pragma unroll
    for (int mm = 0; mm < 4; ++mm) {
      int kcb = (wv * 128 + mm * 32 + kg * 8) * 4;
      f32x4 f0 = *reinterpret_cast<const f32x4*>(ktile + ln16 * 4096 + kcb);
      f32x4 f1 = *reinterpret_cast<const f32x4*>(ktile + ln16 * 4096 + kcb + 16);
      bf16x8 bfr;
      bfr[0] = (bf16)f0[0]; bfr[1] = (bf16)f0[1];
      bfr[2] = (bf16)f0[2]; bfr[3] = (bf16)f0[3];
      bfr[4] = (bf16)f1[0]; bfr[5] = (bf16)f1[1];
      bfr[6] = (bf16)f1[2]; bfr[7] = (bf16)f1[3];
      acc = __builtin_amdgcn_mfma_f32_16x16x32_bf16(afrag[mm], bfr, acc, 0, 0, 0);
    }
    *reinterpret_cast<f32x4*>(&pbuf[wv][ln16][kg * 4]) = acc;
    __syncthreads();

    // reduce partials + exp -> sP + attn (unnormalized)
    if (tid < 256) {
      float s = 0.f;
#pragma unroll
      for (int w = 0; w < 8; ++w) s += pbuf[w][rl][rn];
      float p = __expf((s + qbv) * 0.125f);
      sP[rl][rn] = p;
      attn[((size_t)(rn * NB + b)) * NL + sl * 128 + t * 16 + rl] = p;
    }
    __syncthreads();

    // phase B: ctxa[n] += p[l][n] * k[l][i]; k re-read from global (L2 hit),
    // fully coalesced (64 lanes x 16B = 1KB contiguous per instruction).
#pragma unroll 4
    for (int j = 0; j < 16; ++j) {
      f32x4 kf = *reinterpret_cast<const f32x4*>(ktile + j * 4096 + ic * 16);
      f32x4 p0 = *reinterpret_cast<const f32x4*>(&sP[j][nh * 8]);
      f32x4 p1 = *reinterpret_cast<const f32x4*>(&sP[j][nh * 8 + 4]);
#pragma unroll
      for (int n = 0; n < 4; ++n) ctxa[n] += p0[n] * kf;
#pragma unroll
      for (int n = 0; n < 4; ++n) ctxa[4 + n] += p1[n] * kf;
    }
    // (no third barrier needed: next tile's pbuf write sits behind the
    //  next __syncthreads(), and sP is rewritten only after that barrier)
  }

  // epilogue: direct store, disjoint (nh, ic) -> no cross-thread combine
#pragma unroll
  for (int n = 0; n < 8; ++n)
    *reinterpret_cast<f32x4*>(
        ctxp + (((size_t)sl * NB + b) * NHH + nh * 8 + n) * ND + ic * 4) =
        ctxa[n];
}

// ---------------------------------------------------------------------------
// K4: normalize attn rows (divide by row-sum), write invS. grid=512, block=256
// ---------------------------------------------------------------------------
__global__ __launch_bounds__(256) void norm_kernel(float* __restrict__ attn,
                                                   float* __restrict__ invS) {
  int row = blockIdx.x;
  float* p = attn + (size_t)row * NL;
  int tid = threadIdx.x;
  int lane = tid & 63, wv = tid >> 6;
  float v[8];
  float s = 0.f;
#pragma unroll
  for (int j = 0; j < 8; ++j) {
    v[j] = p[tid + j * 256];
    s += v[j];
  }
#pragma unroll
  for (int off = 32; off > 0; off >>= 1) s += __shfl_down(s, off, 64);
  __shared__ float ss[4];
  if (lane == 0) ss[wv] = s;
  __syncthreads();
  float inv = 1.f / (ss[0] + ss[1] + ss[2] + ss[3]);
  if (tid == 0) invS[row] = inv;
#pragma unroll
  for (int j = 0; j < 8; ++j) p[tid + j * 256] = v[j] * inv;
}

// ---------------------------------------------------------------------------
// K5: ctx = sum_sl ctxp[sl]  (unnormalized). grid=512, block=256, f32x4 each
// ---------------------------------------------------------------------------
__global__ __launch_bounds__(256) void reduce_kernel(
    const float* __restrict__ ctxp, float* __restrict__ ctx) {
  size_t e4 = ((size_t)blockIdx.x * 256 + threadIdx.x) * 4;
  f32x4 s = *reinterpret_cast<const f32x4*>(ctxp + e4);
#pragma unroll
  for (int sl = 1; sl < 16; ++sl)
    s += *reinterpret_cast<const f32x4*>(ctxp + (size_t)sl * NB * NHH * ND + e4);
  *reinterpret_cast<f32x4*>(ctx + e4) = s;
}

// ---------------------------------------------------------------------------
// K6: out[b][o] = (Wv[o].ctx[b][n]) * invS[n*32+b] + bv[o]   grid=1024
// ---------------------------------------------------------------------------
__global__ __launch_bounds__(256) void out_kernel(
    const float* __restrict__ Wv, const float* __restrict__ bv,
    const float* __restrict__ ctx, const float* __restrict__ invS,
    float* __restrict__ out) {
  int o = blockIdx.x;
  int n = o >> 6;
  int lane = threadIdx.x & 63;
  int wv = threadIdx.x >> 6;
  const float4* wrow = reinterpret_cast<const float4*>(Wv + (size_t)o * ND) + lane * 4;
  float4 w0 = wrow[0], w1 = wrow[1], w2 = wrow[2], w3 = wrow[3];
#pragma unroll
  for (int bb = 0; bb < 8; ++bb) {
    int b = wv * 8 + bb;
    const float4* cr =
        reinterpret_cast<const float4*>(ctx + ((size_t)(b * NHH + n)) * ND) + lane * 4;
    float s = dot4(cr[0], w0) + dot4(cr[1], w1) + dot4(cr[2], w2) + dot4(cr[3], w3);
#pragma unroll
    for (int off = 32; off > 0; off >>= 1) s += __shfl_down(s, off, 64);
    if (lane == 0) out[(size_t)b * ND + o] = s * invS[n * NB + b] + bv[o];
  }
}

// ---------------------------------------------------------------------------
extern "C" void kernel_launch(void* const* d_in, const int* in_sizes, int n_in,
                              void* d_out, int out_size, void* d_ws, size_t ws_size,
                              hipStream_t stream) {
  const float* q  = (const float*)d_in[0];
  const float* k  = (const float*)d_in[1];
  const float* Wq = (const float*)d_in[2];
  const float* bq = (const float*)d_in[3];
  const float* Wk = (const float*)d_in[4];
  const float* bk = (const float*)d_in[5];
  const float* Wv = (const float*)d_in[6];
  const float* bv = (const float*)d_in[7];

  float* out  = (float*)d_out;         // [32][1024]
  float* attn = out + NB * ND;         // [512][2048]  (n-major)

  // ws floats: qs 32768 | qt 524288 | qb 512 | invS 512 | ctx 524288 |
  //            ctxp 16*524288
  float* ws   = (float*)d_ws;
  float* qs   = ws;
  float* qt   = qs + 32768;
  float* qb   = qt + 524288;
  float* invS = qb + 512;
  float* ctx  = invS + 512;
  float* ctxp = ctx + 524288;

  qs_kernel<<<1024, 256, 0, stream>>>(q, Wq, bq, qs);
  qt_kernel<<<64, 256, 0, stream>>>(Wk, qs, qt);
  qb_kernel<<<2, 256, 0, stream>>>(qs, bk, qb);
  fused_kernel<<<512, 512, 0, stream>>>(k, qt, qb, attn, ctxp);
  norm_kernel<<<512, 256, 0, stream>>>(attn, invS);
  reduce_kernel<<<512, 256, 0, stream>>>(ctxp, ctx);
  out_kernel<<<1024, 256, 0, stream>>>(Wv, bv, ctx, invS, out);
}

// Round 10
// 123.270 us; speedup vs baseline: 1.1618x; 1.1618x over previous
//
#include <hip/hip_runtime.h>
#include <hip/hip_bf16.h>

// Problem constants
#define NB 32     // batch
#define NL 2048   // seq len
#define ND 1024   // DQ = DK = NH*DH
#define NHH 16    // heads
#define NDH 64    // head dim

typedef __bf16 bf16;
typedef __attribute__((ext_vector_type(4))) __bf16 bf16x4;
typedef __attribute__((ext_vector_type(8))) __bf16 bf16x8;
typedef __attribute__((ext_vector_type(4))) float f32x4;

#define SBAR __builtin_amdgcn_s_barrier()
#define WAIT_LGKM0 asm volatile("s_waitcnt lgkmcnt(0)" ::: "memory")

// two-level row swizzle on 16B/8B granules (proven in R6)
#define SWZ(r) ((((r) & 7) << 4) ^ (((r) & 8) << 2))

__device__ __forceinline__ float dot4(float4 a, float4 b) {
  return a.x * b.x + a.y * b.y + a.z * b.z + a.w * b.w;
}

__device__ __forceinline__ bf16x4 cvt4(f32x4 f) {
  bf16x4 v;
  v[0] = (bf16)f[0]; v[1] = (bf16)f[1]; v[2] = (bf16)f[2]; v[3] = (bf16)f[3];
  return v;
}

// ---------------------------------------------------------------------------
// K1: qs[b][o] = q[b] . Wq[o] + bq[o]      grid=1024, block=256
// ---------------------------------------------------------------------------
__global__ __launch_bounds__(256) void qs_kernel(
    const float* __restrict__ q, const float* __restrict__ Wq,
    const float* __restrict__ bq, float* __restrict__ qs) {
  int o = blockIdx.x;
  int lane = threadIdx.x & 63;
  int wv = threadIdx.x >> 6;
  const float4* wrow = reinterpret_cast<const float4*>(Wq + (size_t)o * ND) + lane * 4;
  float4 w0 = wrow[0], w1 = wrow[1], w2 = wrow[2], w3 = wrow[3];
#pragma unroll
  for (int bb = 0; bb < 8; ++bb) {
    int b = wv * 8 + bb;
    const float4* qr = reinterpret_cast<const float4*>(q + (size_t)b * ND) + lane * 4;
    float s = dot4(qr[0], w0) + dot4(qr[1], w1) + dot4(qr[2], w2) + dot4(qr[3], w3);
#pragma unroll
    for (int off = 32; off > 0; off >>= 1) s += __shfl_down(s, off, 64);
    if (lane == 0) qs[(size_t)b * ND + o] = s + bq[o];
  }
}

// ---------------------------------------------------------------------------
// K2: qt[b][n][i] = sum_d Wk[n*64+d][i] * qs[b][n*64+d]
// grid = 16n x 4ic x 4bg = 256 blocks, block=256. s_qs staged with a
// STRIDED loop (512 entries, 256 threads — R9's bug was `if (tid<512)`).
// ---------------------------------------------------------------------------
__global__ __launch_bounds__(256) void qt_kernel(
    const float* __restrict__ Wk, const float* __restrict__ qs,
    float* __restrict__ qt) {
  int n  = blockIdx.x >> 4;
  int ic = (blockIdx.x >> 2) & 3;
  int bg = blockIdx.x & 3;
  int i = ic * 256 + threadIdx.x;
  __shared__ float s_qs[8][64];
  for (int t = threadIdx.x; t < 512; t += 256) {
    int b = t >> 6, d = t & 63;
    s_qs[b][d] = qs[(size_t)(bg * 8 + b) * ND + n * NDH + d];
  }
  __syncthreads();
  float acc[8];
#pragma unroll
  for (int b = 0; b < 8; ++b) acc[b] = 0.f;
  for (int d = 0; d < 64; ++d) {
    float w = Wk[((size_t)(n * NDH + d)) * ND + i];
#pragma unroll
    for (int b = 0; b < 8; ++b) acc[b] += w * s_qs[b][d];
  }
#pragma unroll
  for (int b = 0; b < 8; ++b)
    qt[((size_t)((bg * 8 + b) * NHH + n)) * ND + i] = acc[b];
}

// ---------------------------------------------------------------------------
// K2b: qb[b*16+n] = qs[b][n*64+:] . bk[n*64+:]    grid=2, block=256
// ---------------------------------------------------------------------------
__global__ __launch_bounds__(256) void qb_kernel(
    const float* __restrict__ qs, const float* __restrict__ bk,
    float* __restrict__ qb) {
  int t = blockIdx.x * 256 + threadIdx.x;
  if (t >= 512) return;
  int b = t >> 4, n = t & 15;
  float s = 0.f;
  for (int d = 0; d < 64; ++d)
    s += qs[(size_t)b * ND + n * NDH + d] * bk[n * NDH + d];
  qb[t] = s;
}

// ---------------------------------------------------------------------------
// K3 (FUSED v6): bf16 LDS dbuf (2x32KB, ~74KB total -> 2 blocks/CU) + T14
// schedule (issue loads in phase A, ds_write after phase B, raw barriers so
// vmcnt never drains at a barrier) + low-DS phase B (thread: 4 heads x 8
// i-cols; per l: one bf16x8 k-read + one broadcast b128 sP read).
// grid = 32b x 16sl = 512 blocks, 512 threads (8 waves).
// ---------------------------------------------------------------------------
__global__ __launch_bounds__(512, 4) void fused_kernel(
    const float* __restrict__ kin, const float* __restrict__ qt,
    const float* __restrict__ qb, float* __restrict__ attn,
    float* __restrict__ ctxp) {
  int bx = blockIdx.x;
  int b  = bx >> 4;
  int sl = bx & 15;
  int tid = threadIdx.x, lane = tid & 63, wv = tid >> 6;
  int kg = lane >> 4;       // 0..3
  int ln16 = lane & 15;

  __shared__ __align__(16) char  kb[2][16 * 1024 * 2];  // 2 x 32 KB bf16
  __shared__ __align__(16) float pbuf[8][16][20];       // [wave][l][n]
  __shared__ __align__(16) float sP[16][20];            // [l][n]

  // afrag: qt[b][n=ln16][wv*128 + mm*32 + kg*8 + 0..7]  (bf16)
  bf16x8 afrag[4];
  {
    const float* qrow = qt + ((size_t)(b * NHH + ln16)) * ND + wv * 128 + kg * 8;
#pragma unroll
    for (int mm = 0; mm < 4; ++mm) {
      f32x4 f0 = *reinterpret_cast<const f32x4*>(qrow + mm * 32);
      f32x4 f1 = *reinterpret_cast<const f32x4*>(qrow + mm * 32 + 4);
      bf16x8 v;
      v[0] = (bf16)f0[0]; v[1] = (bf16)f0[1]; v[2] = (bf16)f0[2]; v[3] = (bf16)f0[3];
      v[4] = (bf16)f1[0]; v[5] = (bf16)f1[1]; v[6] = (bf16)f1[2]; v[7] = (bf16)f1[3];
      afrag[mm] = v;
    }
  }

  // reduce-phase personals (tid<256): (l = tid&15, n = tid>>4)
  int rn = tid >> 4, rl = tid & 15;
  float qbv = (tid < 256) ? qb[b * NHH + rn] : 0.f;

  // phase-B personals: nb = tid>>7 (4 heads each), ig = tid&127 (8 i each)
  int nb = tid >> 7, ig = tid & 127;
  f32x4 ctxa[8];  // [n-of-4][2 x f32x4 i-halves] flattened: n*2 + half
#pragma unroll
  for (int r = 0; r < 8; ++r) ctxa[r] = (f32x4){0.f, 0.f, 0.f, 0.f};

  // stage mapping: row sr = tid>>5 (16 rows), granule sc = tid&31
  int sr = tid >> 5, sc = tid & 31;
  const float* ksrc = kin + ((size_t)(b * NL + sl * 128 + sr)) * ND + sc * 4;

  // prologue: stage tile 0 -> kb[0]
#pragma unroll
  for (int m = 0; m < 8; ++m) {
    f32x4 f = *reinterpret_cast<const f32x4*>(ksrc + m * 128);
    int byte = sr * 2048 + ((sc * 8 + m * 256) ^ SWZ(sr));
    *reinterpret_cast<bf16x4*>(kb[0] + byte) = cvt4(f);
  }
  WAIT_LGKM0;
  SBAR;

  for (int t = 0; t < 8; ++t) {
    int cur = t & 1;
    const char* kbc = kb[cur];

    // 1. issue next tile's global loads (held in regs until after phase B)
    f32x4 ld0, ld1, ld2, ld3, ld4, ld5, ld6, ld7;
    if (t < 7) {
      const float* src = ksrc + (size_t)(t + 1) * 16 * ND;
      ld0 = *reinterpret_cast<const f32x4*>(src);
      ld1 = *reinterpret_cast<const f32x4*>(src + 128);
      ld2 = *reinterpret_cast<const f32x4*>(src + 256);
      ld3 = *reinterpret_cast<const f32x4*>(src + 384);
      ld4 = *reinterpret_cast<const f32x4*>(src + 512);
      ld5 = *reinterpret_cast<const f32x4*>(src + 640);
      ld6 = *reinterpret_cast<const f32x4*>(src + 768);
      ld7 = *reinterpret_cast<const f32x4*>(src + 896);
    }

    // 2. phase A: partial logits; wave covers kc = wv*128 .. +127
    f32x4 acc = {0.f, 0.f, 0.f, 0.f};
#pragma unroll
    for (int mm = 0; mm < 4; ++mm) {
      int kc = wv * 128 + mm * 32 + kg * 8;
      int byteB = ln16 * 2048 + ((kc * 2) ^ SWZ(ln16));
      bf16x8 bfr = *reinterpret_cast<const bf16x8*>(kbc + byteB);
      acc = __builtin_amdgcn_mfma_f32_16x16x32_bf16(afrag[mm], bfr, acc, 0, 0, 0);
    }
    *reinterpret_cast<f32x4*>(&pbuf[wv][ln16][kg * 4]) = acc;
    WAIT_LGKM0;
    SBAR;

    // 3. reduce partials + exp -> sP + attn (unnormalized)
    if (tid < 256) {
      float s = 0.f;
#pragma unroll
      for (int w = 0; w < 8; ++w) s += pbuf[w][rl][rn];
      float p = __expf((s + qbv) * 0.125f);
      sP[rl][rn] = p;
      attn[((size_t)(rn * NB + b)) * NL + sl * 128 + t * 16 + rl] = p;
    }
    WAIT_LGKM0;
    SBAR;

    // 4. phase B: ctxa += p[l][nb*4..+3] * k[l][ig*8..+7]
#pragma unroll 4
    for (int l = 0; l < 16; ++l) {
      bf16x8 kv = *reinterpret_cast<const bf16x8*>(
          kbc + l * 2048 + ((ig * 16) ^ SWZ(l)));
      f32x4 pv = *reinterpret_cast<const f32x4*>(&sP[l][nb * 4]);
      f32x4 k0, k1;
      k0[0] = (float)kv[0]; k0[1] = (float)kv[1];
      k0[2] = (float)kv[2]; k0[3] = (float)kv[3];
      k1[0] = (float)kv[4]; k1[1] = (float)kv[5];
      k1[2] = (float)kv[6]; k1[3] = (float)kv[7];
#pragma unroll
      for (int n = 0; n < 4; ++n) {
        ctxa[n * 2]     += pv[n] * k0;
        ctxa[n * 2 + 1] += pv[n] * k1;
      }
    }

    // 5. stage-write next tile (vmcnt dependency resolves here)
    if (t < 7) {
      char* dst = kb[cur ^ 1];
      int base = sr * 2048;
#define STM(R, M)                                                         \
      *reinterpret_cast<bf16x4*>(dst + base + ((sc * 8 + (M) * 256) ^     \
                                               SWZ(sr))) = cvt4(R);
      STM(ld0, 0) STM(ld1, 1) STM(ld2, 2) STM(ld3, 3)
      STM(ld4, 4) STM(ld5, 5) STM(ld6, 6) STM(ld7, 7)
#undef STM
    }
    WAIT_LGKM0;
    SBAR;
  }

  // epilogue: store slab (disjoint (nb, ig) -> no combine)
#pragma unroll
  for (int n = 0; n < 4; ++n) {
    float* dst = ctxp + (((size_t)sl * NB + b) * NHH + nb * 4 + n) * ND + ig * 8;
    *reinterpret_cast<f32x4*>(dst)     = ctxa[n * 2];
    *reinterpret_cast<f32x4*>(dst + 4) = ctxa[n * 2 + 1];
  }
}

// ---------------------------------------------------------------------------
// K4: normalize attn rows (divide by row-sum), write invS. grid=512, block=256
// ---------------------------------------------------------------------------
__global__ __launch_bounds__(256) void norm_kernel(float* __restrict__ attn,
                                                   float* __restrict__ invS) {
  int row = blockIdx.x;
  float* p = attn + (size_t)row * NL;
  int tid = threadIdx.x;
  int lane = tid & 63, wv = tid >> 6;
  float v[8];
  float s = 0.f;
#pragma unroll
  for (int j = 0; j < 8; ++j) {
    v[j] = p[tid + j * 256];
    s += v[j];
  }
#pragma unroll
  for (int off = 32; off > 0; off >>= 1) s += __shfl_down(s, off, 64);
  __shared__ float ss[4];
  if (lane == 0) ss[wv] = s;
  __syncthreads();
  float inv = 1.f / (ss[0] + ss[1] + ss[2] + ss[3]);
  if (tid == 0) invS[row] = inv;
#pragma unroll
  for (int j = 0; j < 8; ++j) p[tid + j * 256] = v[j] * inv;
}

// ---------------------------------------------------------------------------
// K5: ctx = sum_sl ctxp[sl]  (unnormalized). grid=512, block=256, f32x4 each
// ---------------------------------------------------------------------------
__global__ __launch_bounds__(256) void reduce_kernel(
    const float* __restrict__ ctxp, float* __restrict__ ctx) {
  size_t e4 = ((size_t)blockIdx.x * 256 + threadIdx.x) * 4;
  f32x4 s = *reinterpret_cast<const f32x4*>(ctxp + e4);
#pragma unroll
  for (int sl = 1; sl < 16; ++sl)
    s += *reinterpret_cast<const f32x4*>(ctxp + (size_t)sl * NB * NHH * ND + e4);
  *reinterpret_cast<f32x4*>(ctx + e4) = s;
}

// ---------------------------------------------------------------------------
// K6: out[b][o] = (Wv[o].ctx[b][n]) * invS[n*32+b] + bv[o]   grid=1024
// ---------------------------------------------------------------------------
__global__ __launch_bounds__(256) void out_kernel(
    const float* __restrict__ Wv, const float* __restrict__ bv,
    const float* __restrict__ ctx, const float* __restrict__ invS,
    float* __restrict__ out) {
  int o = blockIdx.x;
  int n = o >> 6;
  int lane = threadIdx.x & 63;
  int wv = threadIdx.x >> 6;
  const float4* wrow = reinterpret_cast<const float4*>(Wv + (size_t)o * ND) + lane * 4;
  float4 w0 = wrow[0], w1 = wrow[1], w2 = wrow[2], w3 = wrow[3];
#pragma unroll
  for (int bb = 0; bb < 8; ++bb) {
    int b = wv * 8 + bb;
    const float4* cr =
        reinterpret_cast<const float4*>(ctx + ((size_t)(b * NHH + n)) * ND) + lane * 4;
    float s = dot4(cr[0], w0) + dot4(cr[1], w1) + dot4(cr[2], w2) + dot4(cr[3], w3);
#pragma unroll
    for (int off = 32; off > 0; off >>= 1) s += __shfl_down(s, off, 64);
    if (lane == 0) out[(size_t)b * ND + o] = s * invS[n * NB + b] + bv[o];
  }
}

// ---------------------------------------------------------------------------
extern "C" void kernel_launch(void* const* d_in, const int* in_sizes, int n_in,
                              void* d_out, int out_size, void* d_ws, size_t ws_size,
                              hipStream_t stream) {
  const float* q  = (const float*)d_in[0];
  const float* k  = (const float*)d_in[1];
  const float* Wq = (const float*)d_in[2];
  const float* bq = (const float*)d_in[3];
  const float* Wk = (const float*)d_in[4];
  const float* bk = (const float*)d_in[5];
  const float* Wv = (const float*)d_in[6];
  const float* bv = (const float*)d_in[7];

  float* out  = (float*)d_out;         // [32][1024]
  float* attn = out + NB * ND;         // [512][2048]  (n-major)

  // ws floats: qs 32768 | qt 524288 | qb 512 | invS 512 | ctx 524288 |
  //            ctxp 16*524288
  float* ws   = (float*)d_ws;
  float* qs   = ws;
  float* qt   = qs + 32768;
  float* qb   = qt + 524288;
  float* invS = qb + 512;
  float* ctx  = invS + 512;
  float* ctxp = ctx + 524288;

  qs_kernel<<<1024, 256, 0, stream>>>(q, Wq, bq, qs);
  qt_kernel<<<256, 256, 0, stream>>>(Wk, qs, qt);
  qb_kernel<<<2, 256, 0, stream>>>(qs, bk, qb);
  fused_kernel<<<512, 512, 0, stream>>>(k, qt, qb, attn, ctxp);
  norm_kernel<<<512, 256, 0, stream>>>(attn, invS);
  reduce_kernel<<<512, 256, 0, stream>>>(ctxp, ctx);
  out_kernel<<<1024, 256, 0, stream>>>(Wv, bv, ctx, invS, out);
}